// Round 1
// baseline (1457.227 us; speedup 1.0000x reference)
//
#include <hip/hip_runtime.h>

#define N_NODES 100000
#define N_EDGES 3200000
#define CH 256

// ---------------- workspace layout (bytes) ----------------
// deg      int[N_NODES]   @ 0
// off      int[N_NODES]   @ 524288
// cursor   int[N_NODES]   @ 1048576
// partial  int[128]       @ 1572864
// edge_src int[N_EDGES]   @ 2097152   (12.8 MB)
// total ~14.9 MB

__global__ void count_deg_k(const int* __restrict__ dst, int* __restrict__ deg) {
    int e = blockIdx.x * 256 + threadIdx.x;
    if (e < N_EDGES) atomicAdd(&deg[dst[e]], 1);
}

__global__ void scan_partial_k(const int* __restrict__ deg, int* __restrict__ partial) {
    __shared__ int sm[256];
    int t = threadIdx.x;
    int base = blockIdx.x * 1024 + t * 4;
    int s = 0;
#pragma unroll
    for (int i = 0; i < 4; ++i) {
        int idx = base + i;
        if (idx < N_NODES) s += deg[idx];
    }
    sm[t] = s;
    __syncthreads();
    for (int st = 128; st > 0; st >>= 1) {
        if (t < st) sm[t] += sm[t + st];
        __syncthreads();
    }
    if (t == 0) partial[blockIdx.x] = sm[0];
}

__global__ void scan_serial_k(int* __restrict__ partial, int nb) {
    if (threadIdx.x == 0 && blockIdx.x == 0) {
        int run = 0;
        for (int i = 0; i < nb; ++i) {
            int v = partial[i];
            partial[i] = run;
            run += v;
        }
    }
}

__global__ void scan_final_k(const int* __restrict__ deg, const int* __restrict__ partial,
                             int* __restrict__ off, int* __restrict__ cursor) {
    __shared__ int sm[256];
    int t = threadIdx.x;
    int base = blockIdx.x * 1024 + t * 4;
    int v[4];
    int s = 0;
#pragma unroll
    for (int i = 0; i < 4; ++i) {
        int idx = base + i;
        v[i] = (idx < N_NODES) ? deg[idx] : 0;
        s += v[i];
    }
    sm[t] = s;
    __syncthreads();
    // exclusive prefix over the 256 thread sums (broadcast reads, tiny kernel)
    int pre = 0;
    for (int j = 0; j < 256; ++j) {
        int xv = sm[j];
        pre += (j < t) ? xv : 0;
    }
    int start = partial[blockIdx.x] + pre;
#pragma unroll
    for (int i = 0; i < 4; ++i) {
        int idx = base + i;
        if (idx < N_NODES) {
            off[idx] = start;
            cursor[idx] = start;
            start += v[i];
        }
    }
}

__global__ void bucket_k(const int* __restrict__ src, const int* __restrict__ dst,
                         int* __restrict__ cursor, int* __restrict__ edge_src) {
    int e = blockIdx.x * 256 + threadIdx.x;
    if (e < N_EDGES) {
        int d = dst[e];
        int pos = atomicAdd(&cursor[d], 1);
        edge_src[pos] = src[e];
    }
}

// one wave per node; lane holds float4 (4 channels): 64 lanes * 4 = 256 ch
__global__ void aggregate_k(const float* __restrict__ x, const int* __restrict__ edge_src,
                            const int* __restrict__ off, const int* __restrict__ deg,
                            float* __restrict__ m) {
    int wid = threadIdx.x >> 6;
    int lane = threadIdx.x & 63;
    int node = blockIdx.x * 4 + wid;  // grid = N_NODES/4 exactly
    int start = off[node];
    int d = deg[node];
    float4 acc = make_float4(0.f, 0.f, 0.f, 0.f);
    for (int e = 0; e < d; ++e) {
        int s = edge_src[start + e];
        const float4 v = *reinterpret_cast<const float4*>(x + (size_t)s * CH + lane * 4);
        acc.x += v.x; acc.y += v.y; acc.z += v.z; acc.w += v.w;
    }
    float inv = 1.0f / (float)(d > 0 ? d : 1);
    acc.x *= inv; acc.y *= inv; acc.z *= inv; acc.w *= inv;
    *reinterpret_cast<float4*>(m + (size_t)node * CH + lane * 4) = acc;
}

// in-place: io holds m (aggregated means); overwritten with m@W + bias*[deg>0].
// Each block owns 64 rows: reads its tile into LDS, then writes back — no aliasing.
__global__ __launch_bounds__(256) void gemm_k(float* __restrict__ io, const float* __restrict__ W,
                                              const float* __restrict__ bias,
                                              const int* __restrict__ deg) {
    __shared__ float sm[64 * 256];  // exactly 64 KB
    int row0 = blockIdx.x * 64;
    int rows = N_NODES - row0;
    if (rows > 64) rows = 64;

    for (int i = threadIdx.x; i < 64 * 64; i += 256) {
        int r = i >> 6;
        int c = (i & 63) * 4;
        if (r < rows) {
            float4 v = *reinterpret_cast<const float4*>(io + (size_t)(row0 + r) * CH + c);
            *reinterpret_cast<float4*>(&sm[r * 256 + c]) = v;
        }
    }
    __syncthreads();

    int cg = (threadIdx.x & 15) * 16;  // 16 output cols
    int rg = (threadIdx.x >> 4) * 4;   // 4 rows

    float acc[4][16];
#pragma unroll
    for (int i = 0; i < 4; ++i)
#pragma unroll
        for (int j = 0; j < 16; ++j) acc[i][j] = 0.f;

    const float* wbase = W + cg;
    for (int k = 0; k < 256; ++k) {
        float a[4];
        a[0] = sm[(rg + 0) * 256 + k];
        a[1] = sm[(rg + 1) * 256 + k];
        a[2] = sm[(rg + 2) * 256 + k];
        a[3] = sm[(rg + 3) * 256 + k];
        const float* wrow = wbase + (size_t)k * CH;
        float wv[16];
        *reinterpret_cast<float4*>(&wv[0])  = *reinterpret_cast<const float4*>(wrow + 0);
        *reinterpret_cast<float4*>(&wv[4])  = *reinterpret_cast<const float4*>(wrow + 4);
        *reinterpret_cast<float4*>(&wv[8])  = *reinterpret_cast<const float4*>(wrow + 8);
        *reinterpret_cast<float4*>(&wv[12]) = *reinterpret_cast<const float4*>(wrow + 12);
#pragma unroll
        for (int i = 0; i < 4; ++i)
#pragma unroll
            for (int j = 0; j < 16; ++j) acc[i][j] = fmaf(a[i], wv[j], acc[i][j]);
    }

    float bv[16];
#pragma unroll
    for (int j = 0; j < 16; ++j) bv[j] = bias[cg + j];

#pragma unroll
    for (int i = 0; i < 4; ++i) {
        int r = rg + i;
        if (r < rows) {
            float bon = (deg[row0 + r] > 0) ? 1.f : 0.f;
            float o[16];
#pragma unroll
            for (int j = 0; j < 16; ++j) o[j] = acc[i][j] + bv[j] * bon;
            float* po = io + (size_t)(row0 + r) * CH + cg;
            *reinterpret_cast<float4*>(po + 0)  = *reinterpret_cast<float4*>(&o[0]);
            *reinterpret_cast<float4*>(po + 4)  = *reinterpret_cast<float4*>(&o[4]);
            *reinterpret_cast<float4*>(po + 8)  = *reinterpret_cast<float4*>(&o[8]);
            *reinterpret_cast<float4*>(po + 12) = *reinterpret_cast<float4*>(&o[12]);
        }
    }
}

extern "C" void kernel_launch(void* const* d_in, const int* in_sizes, int n_in,
                              void* d_out, int out_size, void* d_ws, size_t ws_size,
                              hipStream_t stream) {
    const float* x    = (const float*)d_in[0];
    const int*   src  = (const int*)d_in[1];
    const int*   dst  = (const int*)d_in[2];
    const float* W    = (const float*)d_in[3];
    const float* bias = (const float*)d_in[4];
    float* out = (float*)d_out;

    char* ws = (char*)d_ws;
    int* deg      = (int*)(ws + 0);
    int* off      = (int*)(ws + 524288);
    int* cursor   = (int*)(ws + 1048576);
    int* partial  = (int*)(ws + 1572864);
    int* edge_src = (int*)(ws + 2097152);

    hipMemsetAsync(deg, 0, N_NODES * sizeof(int), stream);

    count_deg_k<<<(N_EDGES + 255) / 256, 256, 0, stream>>>(dst, deg);

    const int NB = (N_NODES + 1023) / 1024;  // 98
    scan_partial_k<<<NB, 256, 0, stream>>>(deg, partial);
    scan_serial_k<<<1, 64, 0, stream>>>(partial, NB);
    scan_final_k<<<NB, 256, 0, stream>>>(deg, partial, off, cursor);

    bucket_k<<<(N_EDGES + 255) / 256, 256, 0, stream>>>(src, dst, cursor, edge_src);

    aggregate_k<<<N_NODES / 4, 256, 0, stream>>>(x, edge_src, off, deg, out);

    gemm_k<<<(N_NODES + 63) / 64, 256, 0, stream>>>(out, W, bias, deg);
}